// Round 12
// baseline (96.966 us; speedup 1.0000x reference)
//
#include <hip/hip_runtime.h>
#include <math.h>

#define BN 4
#define CN 64
#define HN 64
#define WN 256
#define ON 64
#define NOC 18
#define PN 9
#define HO 31
#define WO 127

// LDS V: 64 pixels x 584 shorts (9 taps x 64 ch + 8 pad) = 74752 B
#define VST 584   // shorts per pixel
#define VSB 1168  // bytes per pixel

typedef __attribute__((ext_vector_type(8))) short bf16x8;
typedef __attribute__((ext_vector_type(4))) float f32x4;

__device__ __forceinline__ unsigned short f2bf(float f) {
    unsigned int u = __float_as_uint(f);
    unsigned int r = (u + 0x7fffu + ((u >> 16) & 1u)) >> 16;
    return (unsigned short)r;
}

// packed bf16 convert (RNE): low16 = bf16(lo), high16 = bf16(hi)
__device__ __forceinline__ unsigned int cvtpk(float lo, float hi) {
    unsigned int r;
    asm("v_cvt_pk_bf16_f32 %0, %1, %2" : "=v"(r) : "v"(lo), "v"(hi));
    return r;
}

__device__ __forceinline__ float trianglewave(float x) {
    const float PI_F = 3.14159274101257324f;   // float(np.pi)
    float n = floorf(x / PI_F + 0.5f);
    float m = fmodf(n, 2.0f);
    if (m < 0.0f) m += 2.0f;
    float sgn = 1.0f - 2.0f * m;
    return (x - PI_F * n) * sgn;
}

__device__ __forceinline__ float prak_f(float x) {
    const float PI_HALF = 1.57079637050628662f; // float(np.pi/2)
    return trianglewave(x) + trianglewave(x + PI_HALF);
}

// blocks 0..511: LDS-transposed x[b][c][h][w] (f32) -> x_t[b][h][w][c] (bf16)
// blocks 512..583: weight prep (Wf: 4 m-tiles, WoF: 2 m-tiles, fragment order)
__global__ __launch_bounds__(512) void prep_transpose_kernel(
        const float* __restrict__ x,
        const float* __restrict__ offw,
        const float* __restrict__ wgt,
        unsigned short* __restrict__ xt,
        unsigned short* __restrict__ Wf,
        unsigned short* __restrict__ WoF) {
    if (blockIdx.x < 512) {
        __shared__ float Tl[128][65];
        int blk = blockIdx.x;
        int whalf = blk & 1;
        int h = (blk >> 1) & 63;
        int b = blk >> 7;
        int t = threadIdx.x;
        // read: coalesced rows of x
        int fq = t & 31;           // float4 index within 128-float half row
#pragma unroll
        for (int j = 0; j < 4; j++) {
            int c = (t >> 5) + 16 * j;
            float4 v = *(const float4*)(x + ((size_t)(b * CN + c) * HN + h) * WN + whalf * 128 + fq * 4);
            Tl[fq * 4 + 0][c] = v.x;
            Tl[fq * 4 + 1][c] = v.y;
            Tl[fq * 4 + 2][c] = v.z;
            Tl[fq * 4 + 3][c] = v.w;
        }
        __syncthreads();
        // write: coalesced bf16 rows of xt (8 ch per thread = 16B)
        int cq = t & 7;
#pragma unroll
        for (int j = 0; j < 2; j++) {
            int wl = (t >> 3) + 64 * j;
            uint4 pk;
            pk.x = cvtpk(Tl[wl][cq * 8 + 0], Tl[wl][cq * 8 + 1]);
            pk.y = cvtpk(Tl[wl][cq * 8 + 2], Tl[wl][cq * 8 + 3]);
            pk.z = cvtpk(Tl[wl][cq * 8 + 4], Tl[wl][cq * 8 + 5]);
            pk.w = cvtpk(Tl[wl][cq * 8 + 6], Tl[wl][cq * 8 + 7]);
            *(uint4*)(xt + (((size_t)(b * HN) + h) * WN + whalf * 128 + wl) * 64 + cq * 8) = pk;
        }
    } else {
        int t = (blockIdx.x - 512) * 512 + threadIdx.x;
        if (t < 4 * 18 * 64 * 8) {
            int j    = t & 7;
            int lane = (t >> 3) & 63;
            int rest = t >> 9;          // 0..71
            int ks   = rest % 18;
            int m    = rest / 18;
            int o = m * 16 + (lane & 15);
            int k = ks * 32 + (lane >> 4) * 8 + j;
            int c = k & 63;
            int p = k >> 6;
            Wf[t] = f2bf(wgt[(o * CN + c) * 9 + p]);
        }
        if (t < 2 * 18 * 64 * 8) {
            int j    = t & 7;
            int lane = (t >> 3) & 63;
            int rest = t >> 9;          // 0..35
            int ks   = rest % 18;
            int mo   = rest / 18;
            int o = mo * 16 + (lane & 15);
            int k = ks * 32 + (lane >> 4) * 8 + j;
            int c = k & 63;
            int p = k >> 6;
            WoF[t] = (o < NOC) ? f2bf(offw[(o * CN + c) * 9 + p]) : (unsigned short)0;
        }
    }
}

struct TapS { float w00, w01, w10, w11; int a0, a1, a2, a3; };

// Fully fused: im2col(copy) -> offsets MFMA -> pipelined bf16 gather -> deform MFMA
// -> y write + partial stats -> last block reduces stats (replaces stats_kernel).
// 512 threads = 8 waves per 64-pixel tile; grid 1024 XCD-swizzled; 2 blocks/CU.
__global__ __launch_bounds__(512, 4) void fused_kernel(
        const unsigned short* __restrict__ xt,
        const float* __restrict__ offb,
        const float* __restrict__ mask,
        const unsigned short* __restrict__ WoF,
        const unsigned short* __restrict__ Wf,
        float* __restrict__ y,
        float2* __restrict__ partials,
        float* __restrict__ stats,
        unsigned int* __restrict__ counter) {
    __shared__ __align__(16) unsigned short V[64 * VST];   // 74752 B
    __shared__ float offs_lds[NOC * 64];                   // 4608 B
    __shared__ float red1[8], red2[8];
    __shared__ int amLast;

    int bid = blockIdx.x;
    int logical = ((bid & 7) << 7) + (bid >> 3);   // XCD-chunked
    int b = logical >> 8;
    int h = (logical >> 2) & 63;
    int wblk = logical & 3;
    int lane = threadIdx.x & 63;
    int wv = threadIdx.x >> 6;          // 0..7

    int pl = threadIdx.x >> 3;          // 0..63 (pixel, staging)
    int cg = threadIdx.x & 7;           // 0..7  (8 channels, staging)
    int w = (wblk << 6) + pl;
    const unsigned short* xb = xt + (size_t)b * HN * WN * 64;
    const uint4* xb4 = (const uint4*)xb;    // 8 uint4 per pixel row
    int kq = lane >> 4;

    // ---------- Phase 0: im2col = bf16 bit-copy ----------
#pragma unroll
    for (int p = 0; p < PN; p++) {
        int iy = h + p / 3 - 1;
        int ix = w + p % 3 - 1;
        uint4 pk = {0u, 0u, 0u, 0u};
        if (iy >= 0 && iy < HN && ix >= 0 && ix < WN)
            pk = xb4[((size_t)iy * WN + ix) * 8 + cg];
        *(uint4*)((char*)V + pl * VSB + p * 128 + cg * 16) = pk;
    }
    __syncthreads();

    // ---------- Offsets MFMA: 18x576 @ 576x64 ----------
    {
        int mo = wv >> 2;       // 0..1
        int nt = wv & 3;        // 0..3
        f32x4 acc = {0.0f, 0.0f, 0.0f, 0.0f};
        const bf16x8* Wov = (const bf16x8*)WoF;
        int pixc = nt * 16 + (lane & 15);
        __builtin_amdgcn_s_setprio(1);
#pragma unroll
        for (int ks = 0; ks < 18; ks++) {
            bf16x8 a = Wov[(mo * 18 + ks) * 64 + lane];
            bf16x8 bfr = *(const bf16x8*)((char*)V + pixc * VSB + ks * 64 + kq * 16);
            acc = __builtin_amdgcn_mfma_f32_16x16x32_bf16(a, bfr, acc, 0, 0, 0);
        }
        __builtin_amdgcn_s_setprio(0);
        int ocb = mo * 16 + kq * 4;
#pragma unroll
        for (int r = 0; r < 4; r++) {
            int oc = ocb + r;
            if (oc < NOC) offs_lds[oc * 64 + pixc] = acc[r] + offb[oc];
        }
    }
    __syncthreads();

    // ---------- Phase 1: bf16 gather (2-deep pipelined, overwrites V) ----------
    {
        float mkv[9];
#pragma unroll
        for (int p = 0; p < 9; p++) mkv[p] = mask[((b * PN + p) * HN + h) * WN + w];

        auto stage = [&](int p) -> TapS {
            TapS s;
            float offy = offs_lds[(2 * p) * 64 + pl];
            float offx = offs_lds[(2 * p + 1) * 64 + pl];
            float mk = mkv[p];
            float py = (float)(h + p / 3) + offy;   // padded space
            float px = (float)(w + p % 3) + offx;
            float fy0 = floorf(py), fx0 = floorf(px);
            float wy1 = py - fy0, wx1 = px - fx0;
            float wy0 = 1.0f - wy1, wx0 = 1.0f - wx1;
            int iy0 = (int)fy0 - 1, ix0 = (int)fx0 - 1;
            int iy1 = iy0 + 1, ix1 = ix0 + 1;
            bool vy0 = (iy0 >= 0) && (iy0 < HN);
            bool vy1 = (iy1 >= 0) && (iy1 < HN);
            bool vx0 = (ix0 >= 0) && (ix0 < WN);
            bool vx1 = (ix1 >= 0) && (ix1 < WN);
            s.w00 = (vy0 && vx0) ? wy0 * wx0 * mk : 0.0f;
            s.w01 = (vy0 && vx1) ? wy0 * wx1 * mk : 0.0f;
            s.w10 = (vy1 && vx0) ? wy1 * wx0 * mk : 0.0f;
            s.w11 = (vy1 && vx1) ? wy1 * wx1 * mk : 0.0f;
            int cy0 = min(max(iy0, 0), HN - 1), cy1 = min(max(iy1, 0), HN - 1);
            int cx0 = min(max(ix0, 0), WN - 1), cx1 = min(max(ix1, 0), WN - 1);
            s.a0 = (cy0 * WN + cx0) * 8 + cg;
            s.a1 = (cy0 * WN + cx1) * 8 + cg;
            s.a2 = (cy1 * WN + cx0) * 8 + cg;
            s.a3 = (cy1 * WN + cx1) * 8 + cg;
            return s;
        };

        TapS sC = stage(0);
        uint4 A = xb4[sC.a0], B = xb4[sC.a1], C = xb4[sC.a2], D = xb4[sC.a3];

#pragma unroll
        for (int p = 0; p < 9; p++) {
            TapS sN;
            uint4 nA, nB, nC, nD;
            if (p < 8) {
                sN = stage(p + 1);
                nA = xb4[sN.a0]; nB = xb4[sN.a1];
                nC = xb4[sN.a2]; nD = xb4[sN.a3];
            }
            // unpack bf16 pairs -> f32 (exact: <<16)
            float fa[8], fb[8], fc[8], fd[8];
            {
                unsigned int ua[4] = {A.x, A.y, A.z, A.w};
                unsigned int ub[4] = {B.x, B.y, B.z, B.w};
                unsigned int uc[4] = {C.x, C.y, C.z, C.w};
                unsigned int ud[4] = {D.x, D.y, D.z, D.w};
#pragma unroll
                for (int j = 0; j < 4; j++) {
                    fa[2 * j] = __uint_as_float(ua[j] << 16);
                    fa[2 * j + 1] = __uint_as_float(ua[j] & 0xffff0000u);
                    fb[2 * j] = __uint_as_float(ub[j] << 16);
                    fb[2 * j + 1] = __uint_as_float(ub[j] & 0xffff0000u);
                    fc[2 * j] = __uint_as_float(uc[j] << 16);
                    fc[2 * j + 1] = __uint_as_float(uc[j] & 0xffff0000u);
                    fd[2 * j] = __uint_as_float(ud[j] << 16);
                    fd[2 * j + 1] = __uint_as_float(ud[j] & 0xffff0000u);
                }
            }
            float v[8];
#pragma unroll
            for (int j = 0; j < 8; j++)
                v[j] = sC.w00 * fa[j] + sC.w01 * fb[j] + sC.w10 * fc[j] + sC.w11 * fd[j];
            uint4 pk;
            pk.x = cvtpk(v[0], v[1]);
            pk.y = cvtpk(v[2], v[3]);
            pk.z = cvtpk(v[4], v[5]);
            pk.w = cvtpk(v[6], v[7]);
            *(uint4*)((char*)V + pl * VSB + p * 128 + cg * 16) = pk;
            if (p < 8) {
                sC = sN;
                A = nA; B = nB; C = nC; D = nD;
            }
        }
    }
    __syncthreads();

    // ---------- Phase 2: deform MFMA ----------
    int m = wv >> 1;            // M-tile 0..3
    int npair = wv & 1;         // N-tiles npair*2, npair*2+1
    f32x4 acc0 = {0.0f, 0.0f, 0.0f, 0.0f};
    f32x4 acc1 = {0.0f, 0.0f, 0.0f, 0.0f};
    const bf16x8* Wfv = (const bf16x8*)Wf;
    int pixc = npair * 32 + (lane & 15);
    __builtin_amdgcn_s_setprio(1);
#pragma unroll
    for (int ks = 0; ks < 18; ks++) {
        bf16x8 a  = Wfv[(m * 18 + ks) * 64 + lane];
        bf16x8 b0 = *(const bf16x8*)((char*)V + pixc * VSB + ks * 64 + kq * 16);
        bf16x8 b1 = *(const bf16x8*)((char*)V + (pixc + 16) * VSB + ks * 64 + kq * 16);
        acc0 = __builtin_amdgcn_mfma_f32_16x16x32_bf16(a, b0, acc0, 0, 0, 0);
        acc1 = __builtin_amdgcn_mfma_f32_16x16x32_bf16(a, b1, acc1, 0, 0, 0);
    }
    __builtin_amdgcn_s_setprio(0);

    // C/D layout: col = lane&15 -> pixel; row = (lane>>4)*4 + reg -> o
    int orow = m * 16 + kq * 4;
    float s1 = 0.0f, s2 = 0.0f;
#pragma unroll
    for (int r = 0; r < 4; r++) {
        float v0 = acc0[r];
        float v1 = acc1[r];
        size_t base = (((size_t)(b * ON + orow + r) * HN) + h) * WN + (wblk << 6);
        y[base + pixc] = v0;
        y[base + pixc + 16] = v1;
        s1 += v0 + v1;
        s2 += v0 * v0 + v1 * v1;
    }
#pragma unroll
    for (int off = 32; off > 0; off >>= 1) {
        s1 += __shfl_down(s1, off);
        s2 += __shfl_down(s2, off);
    }
    if (lane == 0) { red1[wv] = s1; red2[wv] = s2; }
    __syncthreads();
    if (threadIdx.x == 0) {
        float t1 = 0.0f, t2 = 0.0f;
#pragma unroll
        for (int i = 0; i < 8; i++) { t1 += red1[i]; t2 += red2[i]; }
        partials[bid] = make_float2(t1, t2);
        __threadfence();
        unsigned int old = atomicAdd(counter, 1u);
        amLast = (old == 1023u) ? 1 : 0;
    }
    __syncthreads();

    // ---------- last block: reduce partials -> stats (bit-identical to old stats_kernel) ----------
    if (amLast) {
        double* dr1 = (double*)V;                 // reuse V (no longer needed)
        double* dr2 = (double*)(V + 2048);        // byte offset 4096
        int tid = threadIdx.x;
        if (tid < 256) {
            double a1 = 0.0, a2 = 0.0;
            for (int i = tid; i < 1024; i += 256) {
                float px = __hip_atomic_load(&partials[i].x, __ATOMIC_RELAXED, __HIP_MEMORY_SCOPE_AGENT);
                float py = __hip_atomic_load(&partials[i].y, __ATOMIC_RELAXED, __HIP_MEMORY_SCOPE_AGENT);
                a1 += (double)px;
                a2 += (double)py;
            }
            dr1[tid] = a1;
            dr2[tid] = a2;
        }
        __syncthreads();
        for (int s = 128; s > 0; s >>= 1) {
            if (tid < s) { dr1[tid] += dr1[tid + s]; dr2[tid] += dr2[tid + s]; }
            __syncthreads();
        }
        if (tid == 0) {
            double N = (double)BN * ON * HN * WN;
            double mu = dr1[0] / N;
            double var = dr2[0] / N - mu * mu;
            stats[0] = (float)mu;
            stats[1] = (float)(1.0 / sqrt(var + 1e-5));
        }
    }
}

// normalize + prak + concat(x) + 3x3/2 maxpool; 4 outputs per thread along ow.
// grid: 4*128*31*32 threads / 256 = 1984 blocks exactly.
__global__ __launch_bounds__(256) void out_kernel(const float* __restrict__ yb,
                                                  const float* __restrict__ x,
                                                  const float* __restrict__ stats,
                                                  float* __restrict__ out) {
    int t = blockIdx.x * 256 + threadIdx.x;
    int q  = t & 31;                 // 4-wide ow group
    int r  = t >> 5;
    int oh = r % 31;
    int cr = r / 31;
    int ch = cr & 127;
    int b  = cr >> 7;

    float mu = stats[0];
    float inv = stats[1];
    float m0 = -INFINITY, m1 = -INFINITY, m2 = -INFINITY, m3 = -INFINITY;
    const float* plane = (ch < 64)
        ? yb + ((size_t)(b * ON + ch) * HN) * WN
        : x + ((size_t)(b * CN + (ch - 64)) * HN) * WN;
    bool doPrak = (ch < 64);

#pragma unroll
    for (int dy = 0; dy < 3; dy++) {
        const float* row = plane + (2 * oh + dy) * WN + 8 * q;
        float2 r0 = *(const float2*)(row + 0);
        float2 r1 = *(const float2*)(row + 2);
        float2 r2 = *(const float2*)(row + 4);
        float2 r3 = *(const float2*)(row + 6);
        float  e8 = row[8];
        float e[9] = {r0.x, r0.y, r1.x, r1.y, r2.x, r2.y, r3.x, r3.y, e8};
        if (doPrak) {
#pragma unroll
            for (int i = 0; i < 9; i++) e[i] = prak_f((e[i] - mu) * inv);
        }
        m0 = fmaxf(m0, fmaxf(fmaxf(e[0], e[1]), e[2]));
        m1 = fmaxf(m1, fmaxf(fmaxf(e[2], e[3]), e[4]));
        m2 = fmaxf(m2, fmaxf(fmaxf(e[4], e[5]), e[6]));
        m3 = fmaxf(m3, fmaxf(fmaxf(e[6], e[7]), e[8]));
    }

    int ow0 = q * 4;
    size_t obase = (((size_t)(b * 128 + ch) * HO) + oh) * WO + ow0;
    out[obase + 0] = m0;
    out[obase + 1] = m1;
    out[obase + 2] = m2;
    if (ow0 + 3 < WO) out[obase + 3] = m3;
}

extern "C" void kernel_launch(void* const* d_in, const int* in_sizes, int n_in,
                              void* d_out, int out_size, void* d_ws, size_t ws_size,
                              hipStream_t stream) {
    const float* x    = (const float*)d_in[0];
    const float* offw = (const float*)d_in[1];
    const float* offb = (const float*)d_in[2];
    const float* wgt  = (const float*)d_in[3];
    const float* mask = (const float*)d_in[4];
    float* out = (float*)d_out;

    unsigned short* Wf  = (unsigned short*)d_ws;          // 36864 bf16
    unsigned short* WoF = Wf + 36864;                     // 18432 bf16
    float* y  = (float*)(WoF + 18432);                    // 4194304 f
    unsigned short* xt = (unsigned short*)(y + 4194304);  // 4194304 bf16
    float2* partials = (float2*)(xt + 4194304);           // 1024 float2
    float* stats = (float*)(partials + 1024);             // 2 f
    unsigned int* counter = (unsigned int*)(stats + 2);   // 1 u32

    hipMemsetAsync(counter, 0, sizeof(unsigned int), stream);
    prep_transpose_kernel<<<584, 512, 0, stream>>>(x, offw, wgt, xt, Wf, WoF);
    fused_kernel<<<1024, 512, 0, stream>>>(xt, offb, mask, WoF, Wf, y, partials, stats, counter);
    out_kernel<<<1984, 256, 0, stream>>>(y, x, stats, out);
}

// Round 13
// 58.660 us; speedup vs baseline: 1.6530x; 1.6530x over previous
//
#include <hip/hip_runtime.h>
#include <math.h>

#define BN 4
#define CN 64
#define HN 64
#define WN 256
#define ON 64
#define NOC 18
#define PN 9
#define HO 31
#define WO 127

// LDS V: 64 pixels x 584 shorts (9 taps x 64 ch + 8 pad) = 74752 B
#define VST 584   // shorts per pixel
#define VSB 1168  // bytes per pixel

typedef __attribute__((ext_vector_type(8))) short bf16x8;
typedef __attribute__((ext_vector_type(4))) float f32x4;

__device__ __forceinline__ unsigned short f2bf(float f) {
    unsigned int u = __float_as_uint(f);
    unsigned int r = (u + 0x7fffu + ((u >> 16) & 1u)) >> 16;
    return (unsigned short)r;
}

// packed bf16 convert (RNE): low16 = bf16(lo), high16 = bf16(hi)
__device__ __forceinline__ unsigned int cvtpk(float lo, float hi) {
    unsigned int r;
    asm("v_cvt_pk_bf16_f32 %0, %1, %2" : "=v"(r) : "v"(lo), "v"(hi));
    return r;
}

__device__ __forceinline__ float trianglewave(float x) {
    const float PI_F = 3.14159274101257324f;   // float(np.pi)
    float n = floorf(x / PI_F + 0.5f);
    float m = fmodf(n, 2.0f);
    if (m < 0.0f) m += 2.0f;
    float sgn = 1.0f - 2.0f * m;
    return (x - PI_F * n) * sgn;
}

__device__ __forceinline__ float prak_f(float x) {
    const float PI_HALF = 1.57079637050628662f; // float(np.pi/2)
    return trianglewave(x) + trianglewave(x + PI_HALF);
}

// blocks 0..511: LDS-transposed x[b][c][h][w] (f32) -> x_t[b][h][w][c] (bf16)
// blocks 512..583: weight prep (Wf: 4 m-tiles, WoF: 2 m-tiles, fragment order)
__global__ __launch_bounds__(512) void prep_transpose_kernel(
        const float* __restrict__ x,
        const float* __restrict__ offw,
        const float* __restrict__ wgt,
        unsigned short* __restrict__ xt,
        unsigned short* __restrict__ Wf,
        unsigned short* __restrict__ WoF) {
    if (blockIdx.x < 512) {
        __shared__ float Tl[128][65];
        int blk = blockIdx.x;
        int whalf = blk & 1;
        int h = (blk >> 1) & 63;
        int b = blk >> 7;
        int t = threadIdx.x;
        // read: coalesced rows of x
        int fq = t & 31;           // float4 index within 128-float half row
#pragma unroll
        for (int j = 0; j < 4; j++) {
            int c = (t >> 5) + 16 * j;
            float4 v = *(const float4*)(x + ((size_t)(b * CN + c) * HN + h) * WN + whalf * 128 + fq * 4);
            Tl[fq * 4 + 0][c] = v.x;
            Tl[fq * 4 + 1][c] = v.y;
            Tl[fq * 4 + 2][c] = v.z;
            Tl[fq * 4 + 3][c] = v.w;
        }
        __syncthreads();
        // write: coalesced bf16 rows of xt (8 ch per thread = 16B)
        int cq = t & 7;
#pragma unroll
        for (int j = 0; j < 2; j++) {
            int wl = (t >> 3) + 64 * j;
            uint4 pk;
            pk.x = cvtpk(Tl[wl][cq * 8 + 0], Tl[wl][cq * 8 + 1]);
            pk.y = cvtpk(Tl[wl][cq * 8 + 2], Tl[wl][cq * 8 + 3]);
            pk.z = cvtpk(Tl[wl][cq * 8 + 4], Tl[wl][cq * 8 + 5]);
            pk.w = cvtpk(Tl[wl][cq * 8 + 6], Tl[wl][cq * 8 + 7]);
            *(uint4*)(xt + (((size_t)(b * HN) + h) * WN + whalf * 128 + wl) * 64 + cq * 8) = pk;
        }
    } else {
        int t = (blockIdx.x - 512) * 512 + threadIdx.x;
        if (t < 4 * 18 * 64 * 8) {
            int j    = t & 7;
            int lane = (t >> 3) & 63;
            int rest = t >> 9;          // 0..71
            int ks   = rest % 18;
            int m    = rest / 18;
            int o = m * 16 + (lane & 15);
            int k = ks * 32 + (lane >> 4) * 8 + j;
            int c = k & 63;
            int p = k >> 6;
            Wf[t] = f2bf(wgt[(o * CN + c) * 9 + p]);
        }
        if (t < 2 * 18 * 64 * 8) {
            int j    = t & 7;
            int lane = (t >> 3) & 63;
            int rest = t >> 9;          // 0..35
            int ks   = rest % 18;
            int mo   = rest / 18;
            int o = mo * 16 + (lane & 15);
            int k = ks * 32 + (lane >> 4) * 8 + j;
            int c = k & 63;
            int p = k >> 6;
            WoF[t] = (o < NOC) ? f2bf(offw[(o * CN + c) * 9 + p]) : (unsigned short)0;
        }
    }
}

struct TapS { float w00, w01, w10, w11; int a0, a1, a2, a3; };

// Fully fused: im2col(copy) -> offsets MFMA -> pipelined bf16 gather -> deform MFMA.
// 512 threads = 8 waves per 64-pixel tile; grid 1024 XCD-swizzled; 2 blocks/CU.
__global__ __launch_bounds__(512, 4) void fused_kernel(
        const unsigned short* __restrict__ xt,
        const float* __restrict__ offb,
        const float* __restrict__ mask,
        const unsigned short* __restrict__ WoF,
        const unsigned short* __restrict__ Wf,
        float* __restrict__ y,
        float2* __restrict__ partials) {
    __shared__ __align__(16) unsigned short V[64 * VST];   // 74752 B
    __shared__ float offs_lds[NOC * 64];                   // 4608 B
    __shared__ float red1[8], red2[8];

    int bid = blockIdx.x;
    int logical = ((bid & 7) << 7) + (bid >> 3);   // XCD-chunked
    int b = logical >> 8;
    int h = (logical >> 2) & 63;
    int wblk = logical & 3;
    int lane = threadIdx.x & 63;
    int wv = threadIdx.x >> 6;          // 0..7

    int pl = threadIdx.x >> 3;          // 0..63 (pixel, staging)
    int cg = threadIdx.x & 7;           // 0..7  (8 channels, staging)
    int w = (wblk << 6) + pl;
    const unsigned short* xb = xt + (size_t)b * HN * WN * 64;
    const uint4* xb4 = (const uint4*)xb;    // 8 uint4 per pixel row
    int kq = lane >> 4;

    // ---------- Phase 0: im2col = bf16 bit-copy ----------
#pragma unroll
    for (int p = 0; p < PN; p++) {
        int iy = h + p / 3 - 1;
        int ix = w + p % 3 - 1;
        uint4 pk = {0u, 0u, 0u, 0u};
        if (iy >= 0 && iy < HN && ix >= 0 && ix < WN)
            pk = xb4[((size_t)iy * WN + ix) * 8 + cg];
        *(uint4*)((char*)V + pl * VSB + p * 128 + cg * 16) = pk;
    }
    __syncthreads();

    // ---------- Offsets MFMA: 18x576 @ 576x64 ----------
    {
        int mo = wv >> 2;       // 0..1
        int nt = wv & 3;        // 0..3
        f32x4 acc = {0.0f, 0.0f, 0.0f, 0.0f};
        const bf16x8* Wov = (const bf16x8*)WoF;
        int pixc = nt * 16 + (lane & 15);
#pragma unroll
        for (int ks = 0; ks < 18; ks++) {
            bf16x8 a = Wov[(mo * 18 + ks) * 64 + lane];
            bf16x8 bfr = *(const bf16x8*)((char*)V + pixc * VSB + ks * 64 + kq * 16);
            acc = __builtin_amdgcn_mfma_f32_16x16x32_bf16(a, bfr, acc, 0, 0, 0);
        }
        int ocb = mo * 16 + kq * 4;
#pragma unroll
        for (int r = 0; r < 4; r++) {
            int oc = ocb + r;
            if (oc < NOC) offs_lds[oc * 64 + pixc] = acc[r] + offb[oc];
        }
    }
    __syncthreads();

    // ---------- Phase 1: bf16 gather (2-deep pipelined, overwrites V) ----------
    {
        float mkv[9];
#pragma unroll
        for (int p = 0; p < 9; p++) mkv[p] = mask[((b * PN + p) * HN + h) * WN + w];

        auto stage = [&](int p) -> TapS {
            TapS s;
            float offy = offs_lds[(2 * p) * 64 + pl];
            float offx = offs_lds[(2 * p + 1) * 64 + pl];
            float mk = mkv[p];
            float py = (float)(h + p / 3) + offy;   // padded space
            float px = (float)(w + p % 3) + offx;
            float fy0 = floorf(py), fx0 = floorf(px);
            float wy1 = py - fy0, wx1 = px - fx0;
            float wy0 = 1.0f - wy1, wx0 = 1.0f - wx1;
            int iy0 = (int)fy0 - 1, ix0 = (int)fx0 - 1;
            int iy1 = iy0 + 1, ix1 = ix0 + 1;
            bool vy0 = (iy0 >= 0) && (iy0 < HN);
            bool vy1 = (iy1 >= 0) && (iy1 < HN);
            bool vx0 = (ix0 >= 0) && (ix0 < WN);
            bool vx1 = (ix1 >= 0) && (ix1 < WN);
            s.w00 = (vy0 && vx0) ? wy0 * wx0 * mk : 0.0f;
            s.w01 = (vy0 && vx1) ? wy0 * wx1 * mk : 0.0f;
            s.w10 = (vy1 && vx0) ? wy1 * wx0 * mk : 0.0f;
            s.w11 = (vy1 && vx1) ? wy1 * wx1 * mk : 0.0f;
            int cy0 = min(max(iy0, 0), HN - 1), cy1 = min(max(iy1, 0), HN - 1);
            int cx0 = min(max(ix0, 0), WN - 1), cx1 = min(max(ix1, 0), WN - 1);
            s.a0 = (cy0 * WN + cx0) * 8 + cg;
            s.a1 = (cy0 * WN + cx1) * 8 + cg;
            s.a2 = (cy1 * WN + cx0) * 8 + cg;
            s.a3 = (cy1 * WN + cx1) * 8 + cg;
            return s;
        };

        TapS sC = stage(0);
        uint4 A = xb4[sC.a0], B = xb4[sC.a1], C = xb4[sC.a2], D = xb4[sC.a3];

#pragma unroll
        for (int p = 0; p < 9; p++) {
            TapS sN;
            uint4 nA, nB, nC, nD;
            if (p < 8) {
                sN = stage(p + 1);
                nA = xb4[sN.a0]; nB = xb4[sN.a1];
                nC = xb4[sN.a2]; nD = xb4[sN.a3];
            }
            // unpack bf16 pairs -> f32 (exact: <<16)
            float fa[8], fb[8], fc[8], fd[8];
            {
                unsigned int ua[4] = {A.x, A.y, A.z, A.w};
                unsigned int ub[4] = {B.x, B.y, B.z, B.w};
                unsigned int uc[4] = {C.x, C.y, C.z, C.w};
                unsigned int ud[4] = {D.x, D.y, D.z, D.w};
#pragma unroll
                for (int j = 0; j < 4; j++) {
                    fa[2 * j] = __uint_as_float(ua[j] << 16);
                    fa[2 * j + 1] = __uint_as_float(ua[j] & 0xffff0000u);
                    fb[2 * j] = __uint_as_float(ub[j] << 16);
                    fb[2 * j + 1] = __uint_as_float(ub[j] & 0xffff0000u);
                    fc[2 * j] = __uint_as_float(uc[j] << 16);
                    fc[2 * j + 1] = __uint_as_float(uc[j] & 0xffff0000u);
                    fd[2 * j] = __uint_as_float(ud[j] << 16);
                    fd[2 * j + 1] = __uint_as_float(ud[j] & 0xffff0000u);
                }
            }
            float v[8];
#pragma unroll
            for (int j = 0; j < 8; j++)
                v[j] = sC.w00 * fa[j] + sC.w01 * fb[j] + sC.w10 * fc[j] + sC.w11 * fd[j];
            uint4 pk;
            pk.x = cvtpk(v[0], v[1]);
            pk.y = cvtpk(v[2], v[3]);
            pk.z = cvtpk(v[4], v[5]);
            pk.w = cvtpk(v[6], v[7]);
            *(uint4*)((char*)V + pl * VSB + p * 128 + cg * 16) = pk;
            if (p < 8) {
                sC = sN;
                A = nA; B = nB; C = nC; D = nD;
            }
        }
    }
    __syncthreads();

    // ---------- Phase 2: deform MFMA ----------
    int m = wv >> 1;            // M-tile 0..3
    int npair = wv & 1;         // N-tiles npair*2, npair*2+1
    f32x4 acc0 = {0.0f, 0.0f, 0.0f, 0.0f};
    f32x4 acc1 = {0.0f, 0.0f, 0.0f, 0.0f};
    const bf16x8* Wfv = (const bf16x8*)Wf;
    int pixc = npair * 32 + (lane & 15);
#pragma unroll
    for (int ks = 0; ks < 18; ks++) {
        bf16x8 a  = Wfv[(m * 18 + ks) * 64 + lane];
        bf16x8 b0 = *(const bf16x8*)((char*)V + pixc * VSB + ks * 64 + kq * 16);
        bf16x8 b1 = *(const bf16x8*)((char*)V + (pixc + 16) * VSB + ks * 64 + kq * 16);
        acc0 = __builtin_amdgcn_mfma_f32_16x16x32_bf16(a, b0, acc0, 0, 0, 0);
        acc1 = __builtin_amdgcn_mfma_f32_16x16x32_bf16(a, b1, acc1, 0, 0, 0);
    }

    // C/D layout: col = lane&15 -> pixel; row = (lane>>4)*4 + reg -> o
    int orow = m * 16 + kq * 4;
    float s1 = 0.0f, s2 = 0.0f;
#pragma unroll
    for (int r = 0; r < 4; r++) {
        float v0 = acc0[r];
        float v1 = acc1[r];
        size_t base = (((size_t)(b * ON + orow + r) * HN) + h) * WN + (wblk << 6);
        y[base + pixc] = v0;
        y[base + pixc + 16] = v1;
        s1 += v0 + v1;
        s2 += v0 * v0 + v1 * v1;
    }
#pragma unroll
    for (int off = 32; off > 0; off >>= 1) {
        s1 += __shfl_down(s1, off);
        s2 += __shfl_down(s2, off);
    }
    if (lane == 0) { red1[wv] = s1; red2[wv] = s2; }
    __syncthreads();
    if (threadIdx.x == 0) {
        float t1 = 0.0f, t2 = 0.0f;
#pragma unroll
        for (int i = 0; i < 8; i++) { t1 += red1[i]; t2 += red2[i]; }
        partials[blockIdx.x] = make_float2(t1, t2);
    }
}

__global__ __launch_bounds__(256) void stats_kernel(const float2* __restrict__ partials,
                                                    int nblocks,
                                                    float* __restrict__ stats) {
    __shared__ double r1[256], r2[256];
    int tid = threadIdx.x;
    double s1 = 0.0, s2 = 0.0;
    for (int i = tid; i < nblocks; i += 256) {
        s1 += (double)partials[i].x;
        s2 += (double)partials[i].y;
    }
    r1[tid] = s1;
    r2[tid] = s2;
    __syncthreads();
    for (int s = 128; s > 0; s >>= 1) {
        if (tid < s) { r1[tid] += r1[tid + s]; r2[tid] += r2[tid + s]; }
        __syncthreads();
    }
    if (tid == 0) {
        double N = (double)BN * ON * HN * WN;
        double mu = r1[0] / N;
        double var = r2[0] / N - mu * mu;
        stats[0] = (float)mu;
        stats[1] = (float)(1.0 / sqrt(var + 1e-5));
    }
}

// normalize + prak + concat(x) + 3x3/2 maxpool; 4 outputs per thread along ow.
// grid: 4*128*31*32 threads / 256 = 1984 blocks exactly.
__global__ __launch_bounds__(256) void out_kernel(const float* __restrict__ yb,
                                                  const float* __restrict__ x,
                                                  const float* __restrict__ stats,
                                                  float* __restrict__ out) {
    int t = blockIdx.x * 256 + threadIdx.x;
    int q  = t & 31;                 // 4-wide ow group
    int r  = t >> 5;
    int oh = r % 31;
    int cr = r / 31;
    int ch = cr & 127;
    int b  = cr >> 7;

    float mu = stats[0];
    float inv = stats[1];
    float m0 = -INFINITY, m1 = -INFINITY, m2 = -INFINITY, m3 = -INFINITY;
    const float* plane = (ch < 64)
        ? yb + ((size_t)(b * ON + ch) * HN) * WN
        : x + ((size_t)(b * CN + (ch - 64)) * HN) * WN;
    bool doPrak = (ch < 64);

#pragma unroll
    for (int dy = 0; dy < 3; dy++) {
        const float* row = plane + (2 * oh + dy) * WN + 8 * q;
        float2 r0 = *(const float2*)(row + 0);
        float2 r1 = *(const float2*)(row + 2);
        float2 r2 = *(const float2*)(row + 4);
        float2 r3 = *(const float2*)(row + 6);
        float  e8 = row[8];
        float e[9] = {r0.x, r0.y, r1.x, r1.y, r2.x, r2.y, r3.x, r3.y, e8};
        if (doPrak) {
#pragma unroll
            for (int i = 0; i < 9; i++) e[i] = prak_f((e[i] - mu) * inv);
        }
        m0 = fmaxf(m0, fmaxf(fmaxf(e[0], e[1]), e[2]));
        m1 = fmaxf(m1, fmaxf(fmaxf(e[2], e[3]), e[4]));
        m2 = fmaxf(m2, fmaxf(fmaxf(e[4], e[5]), e[6]));
        m3 = fmaxf(m3, fmaxf(fmaxf(e[6], e[7]), e[8]));
    }

    int ow0 = q * 4;
    size_t obase = (((size_t)(b * 128 + ch) * HO) + oh) * WO + ow0;
    out[obase + 0] = m0;
    out[obase + 1] = m1;
    out[obase + 2] = m2;
    if (ow0 + 3 < WO) out[obase + 3] = m3;
}

extern "C" void kernel_launch(void* const* d_in, const int* in_sizes, int n_in,
                              void* d_out, int out_size, void* d_ws, size_t ws_size,
                              hipStream_t stream) {
    const float* x    = (const float*)d_in[0];
    const float* offw = (const float*)d_in[1];
    const float* offb = (const float*)d_in[2];
    const float* wgt  = (const float*)d_in[3];
    const float* mask = (const float*)d_in[4];
    float* out = (float*)d_out;

    unsigned short* Wf  = (unsigned short*)d_ws;          // 36864 bf16
    unsigned short* WoF = Wf + 36864;                     // 18432 bf16
    float* y  = (float*)(WoF + 18432);                    // 4194304 f
    unsigned short* xt = (unsigned short*)(y + 4194304);  // 4194304 bf16
    float2* partials = (float2*)(xt + 4194304);           // 1024 float2
    float* stats = (float*)(partials + 1024);             // 2 f

    prep_transpose_kernel<<<584, 512, 0, stream>>>(x, offw, wgt, xt, Wf, WoF);
    fused_kernel<<<1024, 512, 0, stream>>>(xt, offb, mask, WoF, Wf, y, partials);
    stats_kernel<<<1, 256, 0, stream>>>(partials, 1024, stats);
    out_kernel<<<1984, 256, 0, stream>>>(y, x, stats, out);
}